// Round 1
// baseline (663.846 us; speedup 1.0000x reference)
//
#include <hip/hip_runtime.h>

// DiceLoss2: B=16, C=21, H=W=512. Inputs: y_pred (f32), y_true (f32 one-hot), bg (int scalar).
// Output: single f32 scalar.

#define BB 16
#define CC 21
#define HW (512 * 512)
#define SPLIT 64
#define CHUNK (HW / SPLIT)   // 4096 elements per block
#define NBC (BB * CC)        // 336

__global__ void zero_ws_kernel(float* __restrict__ ws, int n) {
    int i = blockIdx.x * blockDim.x + threadIdx.x;
    if (i < n) ws[i] = 0.0f;
}

__global__ __launch_bounds__(256) void dice_reduce_kernel(
    const float* __restrict__ y_pred,
    const float* __restrict__ y_true,
    const int* __restrict__ bg_ptr,
    float* __restrict__ ws)   // ws[3*bc] = {sum_t, sum_p, sum_tp}
{
    const int blk   = blockIdx.x;
    const int split = blk % SPLIT;
    const int bc    = blk / SPLIT;     // 0..NBC-1
    const int c     = bc % CC;
    const int bg    = *bg_ptr;
    if (c < bg) return;                // sliced-away channels contribute nothing

    const size_t base = (size_t)bc * HW + (size_t)split * CHUNK;
    const float4* __restrict__ p4 = (const float4*)(y_pred + base);
    const float4* __restrict__ t4 = (const float4*)(y_true + base);

    float st = 0.0f, sp = 0.0f, stp = 0.0f;
    const int tid = threadIdx.x;

    // CHUNK/4 = 1024 float4s, 256 threads -> 4 iterations, fully coalesced 16B/lane
    #pragma unroll
    for (int i = tid; i < CHUNK / 4; i += 256) {
        float4 p = p4[i];
        float4 t = t4[i];
        sp  += (p.x + p.y) + (p.z + p.w);
        st  += (t.x + t.y) + (t.z + t.w);
        stp += (t.x * p.x + t.y * p.y) + (t.z * p.z + t.w * p.w);
    }

    // wave64 shuffle reduction
    #pragma unroll
    for (int off = 32; off > 0; off >>= 1) {
        st  += __shfl_down(st,  off, 64);
        sp  += __shfl_down(sp,  off, 64);
        stp += __shfl_down(stp, off, 64);
    }

    __shared__ float sm[3][4];
    const int wave = tid >> 6;
    const int lane = tid & 63;
    if (lane == 0) { sm[0][wave] = st; sm[1][wave] = sp; sm[2][wave] = stp; }
    __syncthreads();

    if (tid == 0) {
        float a  = (sm[0][0] + sm[0][1]) + (sm[0][2] + sm[0][3]);
        float b  = (sm[1][0] + sm[1][1]) + (sm[1][2] + sm[1][3]);
        float ab = (sm[2][0] + sm[2][1]) + (sm[2][2] + sm[2][3]);
        atomicAdd(&ws[3 * bc + 0], a);
        atomicAdd(&ws[3 * bc + 1], b);
        atomicAdd(&ws[3 * bc + 2], ab);
    }
}

__global__ __launch_bounds__(256) void dice_final_kernel(
    const float* __restrict__ ws,
    const int* __restrict__ bg_ptr,
    float* __restrict__ out)
{
    const float eps = 1e-11f;
    const int bg = *bg_ptr;
    __shared__ float dice_sum[BB];
    __shared__ int   valid_cnt[BB];

    const int tid = threadIdx.x;
    if (tid < BB) { dice_sum[tid] = 0.0f; valid_cnt[tid] = 0; }
    __syncthreads();

    for (int i = tid; i < NBC; i += blockDim.x) {
        int c = i % CC;
        int b = i / CC;
        if (c < bg) continue;
        float ta    = ws[3 * i + 0];
        float tb    = ws[3 * i + 1];
        float inter = ws[3 * i + 2];
        if (ta != 0.0f) {   // exact: ta is an integer-valued fp32 count
            float dice = 2.0f * inter / (ta + tb + eps);
            atomicAdd(&dice_sum[b], dice);
            atomicAdd(&valid_cnt[b], 1);
        }
    }
    __syncthreads();

    if (tid == 0) {
        float sum_tmp = 0.0f;
        int cpt1 = 0;
        for (int b = 0; b < BB; b++) {
            float denom = (float)valid_cnt[b] - (float)bg;
            if (denom != 0.0f) {
                sum_tmp += dice_sum[b] / denom;
                cpt1++;
            }
        }
        float loss = 1.0f - sum_tmp / fmaxf((float)cpt1, 1.0f);
        out[0] = (cpt1 > 0) ? loss : -1.0f;
    }
}

extern "C" void kernel_launch(void* const* d_in, const int* in_sizes, int n_in,
                              void* d_out, int out_size, void* d_ws, size_t ws_size,
                              hipStream_t stream) {
    const float* y_pred = (const float*)d_in[0];
    const float* y_true = (const float*)d_in[1];
    const int*   bg_ptr = (const int*)d_in[2];
    float* out = (float*)d_out;
    float* ws  = (float*)d_ws;   // 3*NBC floats = 1008 floats

    const int nws = 3 * NBC;
    zero_ws_kernel<<<(nws + 255) / 256, 256, 0, stream>>>(ws, nws);

    dice_reduce_kernel<<<NBC * SPLIT, 256, 0, stream>>>(y_pred, y_true, bg_ptr, ws);

    dice_final_kernel<<<1, 256, 0, stream>>>(ws, bg_ptr, out);
}

// Round 3
// 611.119 us; speedup vs baseline: 1.0863x; 1.0863x over previous
//
#include <hip/hip_runtime.h>

// DiceLoss2: B=16, C=21, H=W=512. Inputs: y_pred (f32), y_true (f32 one-hot), bg (int scalar).
// Output: single f32 scalar.
//
// Structure: (1) atomic-free split reduction — each block reduces a contiguous
// 16K-element chunk of one (b,c) plane and writes 3 private partials;
// (2) one-block epilogue reduces 336x16 partials and computes the loss.

#define BB 16
#define CC 21
#define HW (512 * 512)
#define SPLIT 16
#define CHUNK (HW / SPLIT)      // 16384 elements per block
#define NBC (BB * CC)           // 336
#define NPART (NBC * SPLIT)     // 5376 partial slots per quantity

// Native clang vector type: __builtin_nontemporal_load requires a pointer to
// int/float/pointer or a VECTOR of such — HIP's float4 is a struct and fails.
typedef float floatx4 __attribute__((ext_vector_type(4)));

__global__ __launch_bounds__(256) void dice_reduce_kernel(
    const float* __restrict__ y_pred,
    const float* __restrict__ y_true,
    const int* __restrict__ bg_ptr,
    float* __restrict__ part)   // [3][NPART]: st, sp, stp
{
    const int blk   = blockIdx.x;
    const int split = blk % SPLIT;
    const int bc    = blk / SPLIT;     // 0..NBC-1
    const int c     = bc % CC;
    const int bg    = *bg_ptr;
    if (c < bg) return;                // sliced-away channel: final kernel skips its slots

    const size_t base = (size_t)bc * HW + (size_t)split * CHUNK;
    const floatx4* __restrict__ p4 = (const floatx4*)(y_pred + base);
    const floatx4* __restrict__ t4 = (const floatx4*)(y_true + base);

    float st = 0.0f, sp = 0.0f, stp = 0.0f;
    const int tid = threadIdx.x;

    // CHUNK/4 = 4096 float4s, 256 threads -> 16 iterations, coalesced 16B/lane.
    // Nontemporal: data is touched exactly once, don't pollute L2.
    #pragma unroll 4
    for (int i = tid; i < CHUNK / 4; i += 256) {
        floatx4 p = __builtin_nontemporal_load(&p4[i]);
        floatx4 t = __builtin_nontemporal_load(&t4[i]);
        sp  += (p.x + p.y) + (p.z + p.w);
        st  += (t.x + t.y) + (t.z + t.w);
        stp += (t.x * p.x + t.y * p.y) + (t.z * p.z + t.w * p.w);
    }

    // wave64 shuffle reduction
    #pragma unroll
    for (int off = 32; off > 0; off >>= 1) {
        st  += __shfl_down(st,  off, 64);
        sp  += __shfl_down(sp,  off, 64);
        stp += __shfl_down(stp, off, 64);
    }

    __shared__ float sm[3][4];
    const int wave = tid >> 6;
    const int lane = tid & 63;
    if (lane == 0) { sm[0][wave] = st; sm[1][wave] = sp; sm[2][wave] = stp; }
    __syncthreads();

    if (tid == 0) {
        part[0 * NPART + blk] = (sm[0][0] + sm[0][1]) + (sm[0][2] + sm[0][3]);
        part[1 * NPART + blk] = (sm[1][0] + sm[1][1]) + (sm[1][2] + sm[1][3]);
        part[2 * NPART + blk] = (sm[2][0] + sm[2][1]) + (sm[2][2] + sm[2][3]);
    }
}

__global__ __launch_bounds__(384) void dice_final_kernel(
    const float* __restrict__ part,
    const int* __restrict__ bg_ptr,
    float* __restrict__ out)
{
    const float eps = 1e-11f;
    const int bg = *bg_ptr;
    __shared__ float dice_sum[BB];
    __shared__ int   valid_cnt[BB];

    const int tid = threadIdx.x;
    if (tid < BB) { dice_sum[tid] = 0.0f; valid_cnt[tid] = 0; }
    __syncthreads();

    if (tid < NBC) {
        const int c = tid % CC;
        const int b = tid / CC;
        if (c >= bg) {
            float ta = 0.0f, tb = 0.0f, inter = 0.0f;
            #pragma unroll
            for (int s = 0; s < SPLIT; s++) {
                ta    += part[0 * NPART + tid * SPLIT + s];
                tb    += part[1 * NPART + tid * SPLIT + s];
                inter += part[2 * NPART + tid * SPLIT + s];
            }
            if (ta != 0.0f) {   // exact: ta is an integer-valued fp32 count < 2^24
                float dice = 2.0f * inter / (ta + tb + eps);
                atomicAdd(&dice_sum[b], dice);
                atomicAdd(&valid_cnt[b], 1);
            }
        }
    }
    __syncthreads();

    if (tid == 0) {
        float sum_tmp = 0.0f;
        int cpt1 = 0;
        for (int b = 0; b < BB; b++) {
            float denom = (float)valid_cnt[b] - (float)bg;
            if (denom != 0.0f) {
                sum_tmp += dice_sum[b] / denom;
                cpt1++;
            }
        }
        float loss = 1.0f - sum_tmp / fmaxf((float)cpt1, 1.0f);
        out[0] = (cpt1 > 0) ? loss : -1.0f;
    }
}

extern "C" void kernel_launch(void* const* d_in, const int* in_sizes, int n_in,
                              void* d_out, int out_size, void* d_ws, size_t ws_size,
                              hipStream_t stream) {
    const float* y_pred = (const float*)d_in[0];
    const float* y_true = (const float*)d_in[1];
    const int*   bg_ptr = (const int*)d_in[2];
    float* out  = (float*)d_out;
    float* part = (float*)d_ws;   // 3 * NPART floats = 64.5 KB, no init needed

    dice_reduce_kernel<<<NBC * SPLIT, 256, 0, stream>>>(y_pred, y_true, bg_ptr, part);
    dice_final_kernel<<<1, 384, 0, stream>>>(part, bg_ptr, out);
}